// Round 11
// baseline (29.634 us; speedup 1.0000x reference)
//
#include <hip/hip_runtime.h>
#include <stdint.h>

#define NB 4096
#define QLEN 1024
#define NL 64
#define KLEN 32
#define NS (QLEN - KLEN + 1)   // 993

typedef __attribute__((ext_vector_type(8))) _Float16 half8;
typedef __attribute__((ext_vector_type(4))) float f32x4;

union fragh { uint32_t u[4]; half8 v; };

static __device__ __forceinline__ uint32_t pkh(float a, float b) {
    return __builtin_bit_cast(uint32_t, __builtin_amdgcn_cvt_pkrtz(a, b)); // v_cvt_pkrtz_f16_f32
}
static __device__ __forceinline__ float lo16f(uint32_t w) {
    return (float)__builtin_bit_cast(_Float16, (unsigned short)(w & 0xFFFFu));
}
static __device__ __forceinline__ float hi16f(uint32_t w) {
    return (float)__builtin_bit_cast(_Float16, (unsigned short)(w >> 16));
}
static __device__ __forceinline__ uint32_t pkh_rne(float a, float b) {  // RNE f16 pair
    unsigned short ha = __builtin_bit_cast(unsigned short, (_Float16)a);
    unsigned short hb = __builtin_bit_cast(unsigned short, (_Float16)b);
    return (uint32_t)ha | ((uint32_t)hb << 16);
}

__global__ __launch_bounds__(256, 4) void shapelet_r11(
    const float* __restrict__ ts,        // [B, Q]
    const float* __restrict__ shapelets, // [L, K]
    const float* __restrict__ fc_w,      // [2, L]
    const float* __restrict__ fc_b,      // [2]
    float* __restrict__ out)             // [B, 2]
{
    __shared__ __align__(16) uint32_t lds_pkE[544];   // f16(x[2i]) | f16(x[2i+1])<<16
    __shared__ __align__(16) uint32_t lds_pkO[544];   // f16(x[2i+1]) | f16(x[2i+2])<<16
    __shared__ __align__(16) uint32_t lds_nwh[512];   // -0.5*win as f16 pairs, MFMA-frag layout
    __shared__ __align__(16) float    lds_s4[264];    // per-thread 4-square partials
    __shared__ float lds_ssq[NL];
    __shared__ float lds_pm[4][NL];

    const int tid  = threadIdx.x;
    const int b    = blockIdx.x;
    const int lane = tid & 63;
    const int wave = tid >> 6;
    const int col  = lane & 15;
    const int kg   = lane >> 4;

    // --- pass 1: own float4 + next dword from global; pack f16; s4 partial ---
    float x0, x1, x2;
    {
        float4 v = reinterpret_cast<const float4*>(ts + (size_t)b * QLEN)[tid];
        x0 = v.x; x1 = v.y; x2 = v.z;
        float x3 = v.w;
        float x4g = (tid < 255) ? ts[(size_t)b * QLEN + 4 * tid + 4] : 0.0f;
        uint2 pe = { pkh(x0, x1), pkh(x2, x3) };
        uint2 po = { pkh(x1, x2), pkh(x3, x4g) };
        reinterpret_cast<uint2*>(lds_pkE)[tid] = pe;
        reinterpret_cast<uint2*>(lds_pkO)[tid] = po;
        lds_s4[tid] = fmaf(x0, x0, fmaf(x1, x1, fmaf(x2, x2, x3 * x3)));
    }
    if (tid < 32) { lds_pkE[512 + tid] = 0u; lds_pkO[512 + tid] = 0u; }
    if (tid < 8)  lds_s4[256 + tid] = 0.0f;

    // --- B fragments: fp16 RTZ, all 4 l-tiles (16 VGPR) ---
    fragh Bh[4];
    #pragma unroll
    for (int lt = 0; lt < 4; ++lt) {
        const float* sp = shapelets + (lt * 16 + col) * KLEN + kg * 8;
        float4 f0 = *reinterpret_cast<const float4*>(sp);
        float4 f1 = *reinterpret_cast<const float4*>(sp + 4);
        Bh[lt].u[0] = pkh(f0.x, f0.y);
        Bh[lt].u[1] = pkh(f0.z, f0.w);
        Bh[lt].u[2] = pkh(f1.x, f1.y);
        Bh[lt].u[3] = pkh(f1.z, f1.w);
    }

    // --- per-shapelet sum of squares (fp32, global reads, L2-cached) ---
    if (tid < NL) {
        const float* sp = shapelets + tid * KLEN;
        float s = 0.0f;
        #pragma unroll
        for (int k = 0; k < KLEN; ++k) s = fmaf(sp[k], sp[k], s);
        lds_ssq[tid] = s;
    }
    __syncthreads();

    // --- pass 2: win_sq from s4 partials + f16 sliding corrections;
    //     store -0.5*win as f16 pairs in the per-(tilepair,kg) fragment layout ---
    {
        float s[8];
        #pragma unroll
        for (int j = 0; j < 8; ++j) s[j] = lds_s4[tid + j];
        float w0 = ((s[0] + s[1]) + (s[2] + s[3])) + ((s[4] + s[5]) + (s[6] + s[7]));
        uint32_t cw0 = lds_pkE[2 * (tid + 8)];
        uint32_t cw1 = lds_pkE[2 * (tid + 8) + 1];
        float x32 = lo16f(cw0), x33 = hi16f(cw0), x34 = lo16f(cw1);
        float w1 = fmaf(x32, x32, fmaf(-x0, x0, w0));
        float w2 = fmaf(x33, x33, fmaf(-x1, x1, w1));
        float w3 = fmaf(x34, x34, fmaf(-x2, x2, w2));
        const int p0 = 4 * tid;
        float c0 = (p0 + 0 < NS) ? -0.5f * w0 : -60000.0f;
        float c1 = (p0 + 1 < NS) ? -0.5f * w1 : -60000.0f;
        float c2 = (p0 + 2 < NS) ? -0.5f * w2 : -60000.0f;
        float c3 = (p0 + 3 < NS) ? -0.5f * w3 : -60000.0f;
        // word index: W = 16*t + 4*kg' + 2*(half) with t=p>>5, kg'=(p&15)>>2, half=(p&31)>>4
        const int q = p0 & 31;
        const int W = ((p0 >> 5) << 4) + (((q & 15) >> 2) << 2) + ((q >> 4) << 1);
        uint2 hw = { pkh_rne(c0, c1), pkh_rne(c2, c3) };
        *reinterpret_cast<uint2*>(&lds_nwh[W]) = hw;
    }
    __syncthreads();

    // --- main loop: identical body to r10; unroll 4 + VGPR cap 128 for a
    //     4-iteration scheduling window (32 independent MFMAs in flight) ---
    float rmax[4][4];
    #pragma unroll
    for (int lt = 0; lt < 4; ++lt)
        #pragma unroll
        for (int e = 0; e < 4; ++e) rmax[lt][e] = -3.0e38f;

    const int par = col & 1;
    const uint32_t* apk = par ? lds_pkO : lds_pkE;
    const int abase = ((col - par) >> 1) + kg * 4;
    const int nwb = 4 * kg;

    #pragma unroll 4
    for (int i = 0; i < 8; ++i) {
        const int s0 = 32 * wave + 128 * i;
        const int tp = wave + 4 * i;                  // tile-pair index
        const uint32_t* ap = apk + (s0 >> 1) + abase;
        fragh Aa, Ab;
        #pragma unroll
        for (int j = 0; j < 4; ++j) Aa.u[j] = ap[j];
        #pragma unroll
        for (int j = 0; j < 4; ++j) Ab.u[j] = ap[8 + j];

        uint4 nw = *reinterpret_cast<const uint4*>(&lds_nwh[16 * tp + nwb]);
        f32x4 ia, ib;
        ia[0] = lo16f(nw.x); ia[1] = hi16f(nw.x);
        ia[2] = lo16f(nw.y); ia[3] = hi16f(nw.y);
        ib[0] = lo16f(nw.z); ib[1] = hi16f(nw.z);
        ib[2] = lo16f(nw.w); ib[3] = hi16f(nw.w);

        #pragma unroll
        for (int lt = 0; lt < 4; ++lt) {
            f32x4 aa = __builtin_amdgcn_mfma_f32_16x16x32_f16(Aa.v, Bh[lt].v, ia, 0, 0, 0);
            f32x4 ab = __builtin_amdgcn_mfma_f32_16x16x32_f16(Ab.v, Bh[lt].v, ib, 0, 0, 0);
            #pragma unroll
            for (int e = 0; e < 4; ++e)
                rmax[lt][e] = fmaxf(fmaxf(aa[e], ab[e]), rmax[lt][e]);  // v_max3_f32
        }
    }

    // --- reduce: within-lane, cross-kg (same col), cross-wave ---
    #pragma unroll
    for (int lt = 0; lt < 4; ++lt) {
        float v = fmaxf(fmaxf(rmax[lt][0], rmax[lt][1]),
                        fmaxf(rmax[lt][2], rmax[lt][3]));
        v = fmaxf(v, __shfl_xor(v, 16, 64));
        v = fmaxf(v, __shfl_xor(v, 32, 64));
        if (kg == 0) lds_pm[wave][lt * 16 + col] = v;
    }
    __syncthreads();

    if (wave == 0) {
        float m = fmaxf(fmaxf(lds_pm[0][lane], lds_pm[1][lane]),
                        fmaxf(lds_pm[2][lane], lds_pm[3][lane]));
        float f = (lds_ssq[lane] - 2.0f * m) * (1.0f / (float)KLEN);  // min dist

        float p0v = f * fc_w[lane];
        float p1v = f * fc_w[NL + lane];
        #pragma unroll
        for (int off = 32; off >= 1; off >>= 1) {
            p0v += __shfl_xor(p0v, off, 64);
            p1v += __shfl_xor(p1v, off, 64);
        }
        if (lane == 0) {
            out[(size_t)b * 2 + 0] = p0v + fc_b[0];
            out[(size_t)b * 2 + 1] = p1v + fc_b[1];
        }
    }
}

extern "C" void kernel_launch(void* const* d_in, const int* in_sizes, int n_in,
                              void* d_out, int out_size, void* d_ws, size_t ws_size,
                              hipStream_t stream) {
    const float* ts        = (const float*)d_in[0];
    const float* shapelets = (const float*)d_in[1];
    const float* fc_w      = (const float*)d_in[2];
    const float* fc_b      = (const float*)d_in[3];
    float* out = (float*)d_out;

    shapelet_r11<<<NB, 256, 0, stream>>>(ts, shapelets, fc_w, fc_b, out);
}

// Round 12
// 23.798 us; speedup vs baseline: 1.2452x; 1.2452x over previous
//
#include <hip/hip_runtime.h>
#include <stdint.h>

#define NB 4096
#define QLEN 1024
#define NL 64
#define KLEN 32
#define NS (QLEN - KLEN + 1)   // 993
#define WSLICE 1856            // u32 per wave LDS slice (multiple of 32)

typedef __attribute__((ext_vector_type(8))) _Float16 half8;
typedef __attribute__((ext_vector_type(4))) float f32x4;

union fragh { uint32_t u[4]; half8 v; };

static __device__ __forceinline__ uint32_t pkh(float a, float b) {
    return __builtin_bit_cast(uint32_t, __builtin_amdgcn_cvt_pkrtz(a, b)); // v_cvt_pkrtz_f16_f32
}
static __device__ __forceinline__ float lo16f(uint32_t w) {
    return (float)__builtin_bit_cast(_Float16, (unsigned short)(w & 0xFFFFu));
}
static __device__ __forceinline__ float hi16f(uint32_t w) {
    return (float)__builtin_bit_cast(_Float16, (unsigned short)(w >> 16));
}
static __device__ __forceinline__ uint32_t pkh_rne(float a, float b) {  // RNE f16 pair
    unsigned short ha = __builtin_bit_cast(unsigned short, (_Float16)a);
    unsigned short hb = __builtin_bit_cast(unsigned short, (_Float16)b);
    return (uint32_t)ha | ((uint32_t)hb << 16);
}

__global__ __launch_bounds__(256, 4) void shapelet_r12(
    const float* __restrict__ ts,        // [B, Q]
    const float* __restrict__ shapelets, // [L, K]
    const float* __restrict__ fc_w,      // [2, L]
    const float* __restrict__ fc_b,      // [2]
    float* __restrict__ out)             // [B, 2]
{
    // 4 private slices, one per wave; NO __syncthreads in this kernel.
    __shared__ __align__(16) uint32_t lds[4 * WSLICE];   // 29.7 KB

    const int tid  = threadIdx.x;
    const int wave = tid >> 6;
    const int lane = tid & 63;
    const int col  = lane & 15;
    const int kg   = lane >> 4;
    const int row  = blockIdx.x * 4 + wave;   // this wave's batch row

    uint32_t* pkE = lds + wave * WSLICE;                   // [528] f16(x[2i])|f16(x[2i+1])<<16
    uint32_t* pkO = pkE + 528;                             // [528] odd-phase pairs
    uint32_t* nwh = pkO + 528;                             // [512] -0.5*win f16 pairs, frag layout
    float*    s4  = reinterpret_cast<float*>(nwh + 512);   // [264] 4-square partials

    // --- pass 1: wave loads its whole row (4 float4/lane), packs, partials ---
    const float* rowp = ts + (size_t)row * QLEN;
    float4 v[4];
    #pragma unroll
    for (int c = 0; c < 4; ++c)
        v[c] = reinterpret_cast<const float4*>(rowp)[64 * c + lane];
    float x4[4];
    #pragma unroll
    for (int c = 0; c < 4; ++c) {
        const int p = 256 * c + 4 * lane + 4;
        x4[c] = (p < QLEN) ? rowp[p] : 0.0f;    // L1-hit (same lines as float4s)
    }
    #pragma unroll
    for (int c = 0; c < 4; ++c) {
        uint2 pe = { pkh(v[c].x, v[c].y), pkh(v[c].z, v[c].w) };
        uint2 po = { pkh(v[c].y, v[c].z), pkh(v[c].w, x4[c]) };
        reinterpret_cast<uint2*>(pkE)[64 * c + lane] = pe;
        reinterpret_cast<uint2*>(pkO)[64 * c + lane] = po;
        s4[64 * c + lane] =
            fmaf(v[c].x, v[c].x, fmaf(v[c].y, v[c].y, fmaf(v[c].z, v[c].z, v[c].w * v[c].w)));
    }
    if (lane < 16) { pkE[512 + lane] = 0u; pkO[512 + lane] = 0u; }
    if (lane < 8)  s4[256 + lane] = 0.0f;

    // --- B fragments (fp16 RTZ) + exact fp32 ssq partials from the same temps ---
    fragh Bh[4];
    float ssq[4];
    #pragma unroll
    for (int lt = 0; lt < 4; ++lt) {
        const float* sp = shapelets + (lt * 16 + col) * KLEN + kg * 8;
        float4 f0 = *reinterpret_cast<const float4*>(sp);
        float4 f1 = *reinterpret_cast<const float4*>(sp + 4);
        Bh[lt].u[0] = pkh(f0.x, f0.y);
        Bh[lt].u[1] = pkh(f0.z, f0.w);
        Bh[lt].u[2] = pkh(f1.x, f1.y);
        Bh[lt].u[3] = pkh(f1.z, f1.w);
        float s = f0.x * f0.x;
        s = fmaf(f0.y, f0.y, s); s = fmaf(f0.z, f0.z, s); s = fmaf(f0.w, f0.w, s);
        s = fmaf(f1.x, f1.x, s); s = fmaf(f1.y, f1.y, s);
        s = fmaf(f1.z, f1.z, s); s = fmaf(f1.w, f1.w, s);
        ssq[lt] = s;   // kg-partial; reduced in epilogue
    }

    __builtin_amdgcn_wave_barrier();   // order pass-1 LDS writes before pass-2 reads

    // --- pass 2: win_sq from s4 partials + f16 sliding corrections -> nwh ---
    #pragma unroll
    for (int c = 0; c < 4; ++c) {
        const int q = 64 * c + lane;
        float s_[8];
        #pragma unroll
        for (int j = 0; j < 8; ++j) s_[j] = s4[q + j];
        float w0 = ((s_[0] + s_[1]) + (s_[2] + s_[3])) + ((s_[4] + s_[5]) + (s_[6] + s_[7]));
        uint32_t cw0 = pkE[2 * (q + 8)];
        uint32_t cw1 = pkE[2 * (q + 8) + 1];
        float x32 = lo16f(cw0), x33 = hi16f(cw0), x34 = lo16f(cw1);
        float w1 = fmaf(x32, x32, fmaf(-v[c].x, v[c].x, w0));
        float w2 = fmaf(x33, x33, fmaf(-v[c].y, v[c].y, w1));
        float w3 = fmaf(x34, x34, fmaf(-v[c].z, v[c].z, w2));
        const int p0 = 4 * q;
        float c0 = (p0 + 0 < NS) ? -0.5f * w0 : -60000.0f;
        float c1 = (p0 + 1 < NS) ? -0.5f * w1 : -60000.0f;
        float c2 = (p0 + 2 < NS) ? -0.5f * w2 : -60000.0f;
        float c3 = (p0 + 3 < NS) ? -0.5f * w3 : -60000.0f;
        const int qq = p0 & 31;
        const int W = ((p0 >> 5) << 4) + (((qq & 15) >> 2) << 2) + ((qq >> 4) << 1);
        uint2 hw = { pkh_rne(c0, c1), pkh_rne(c2, c3) };
        *reinterpret_cast<uint2*>(&nwh[W]) = hw;
    }

    __builtin_amdgcn_wave_barrier();   // order pass-2 stores before main-loop reads

    // --- main loop: 32 tile-pairs, r10's exact iteration body, no barriers ---
    float rmax[4][4];
    #pragma unroll
    for (int lt = 0; lt < 4; ++lt)
        #pragma unroll
        for (int e = 0; e < 4; ++e) rmax[lt][e] = -3.0e38f;

    const int par = col & 1;
    const uint32_t* apk = (par ? pkO : pkE) + (((col - par) >> 1) + kg * 4);
    const int nwb = 4 * kg;

    #pragma unroll 2
    for (int i = 0; i < 32; ++i) {
        const uint32_t* ap = apk + 16 * i;
        fragh Aa, Ab;
        #pragma unroll
        for (int j = 0; j < 4; ++j) Aa.u[j] = ap[j];
        #pragma unroll
        for (int j = 0; j < 4; ++j) Ab.u[j] = ap[8 + j];

        uint4 nw = *reinterpret_cast<const uint4*>(&nwh[16 * i + nwb]);
        f32x4 ia, ib;
        ia[0] = lo16f(nw.x); ia[1] = hi16f(nw.x);
        ia[2] = lo16f(nw.y); ia[3] = hi16f(nw.y);
        ib[0] = lo16f(nw.z); ib[1] = hi16f(nw.z);
        ib[2] = lo16f(nw.w); ib[3] = hi16f(nw.w);

        #pragma unroll
        for (int lt = 0; lt < 4; ++lt) {
            f32x4 aa = __builtin_amdgcn_mfma_f32_16x16x32_f16(Aa.v, Bh[lt].v, ia, 0, 0, 0);
            f32x4 ab = __builtin_amdgcn_mfma_f32_16x16x32_f16(Ab.v, Bh[lt].v, ib, 0, 0, 0);
            #pragma unroll
            for (int e = 0; e < 4; ++e)
                rmax[lt][e] = fmaxf(fmaxf(aa[e], ab[e]), rmax[lt][e]);  // v_max3_f32
        }
    }

    // --- epilogue: all in-wave shuffles, no LDS, no barrier ---
    float p0v = 0.0f, p1v = 0.0f;
    #pragma unroll
    for (int lt = 0; lt < 4; ++lt) {
        float m = fmaxf(fmaxf(rmax[lt][0], rmax[lt][1]),
                        fmaxf(rmax[lt][2], rmax[lt][3]));
        m = fmaxf(m, __shfl_xor(m, 16, 64));
        m = fmaxf(m, __shfl_xor(m, 32, 64));      // all lanes: max over all 16 rows
        float sq = ssq[lt];
        sq += __shfl_xor(sq, 16, 64);
        sq += __shfl_xor(sq, 32, 64);             // all lanes: exact ssq
        float f = (sq - 2.0f * m) * (1.0f / (float)KLEN);   // feat[row, lt*16+col]
        p0v = fmaf(f, fc_w[lt * 16 + col], p0v);
        p1v = fmaf(f, fc_w[NL + lt * 16 + col], p1v);
    }
    // sum over col (each 16-lane group holds identical copies -> sum within group)
    #pragma unroll
    for (int off = 1; off <= 8; off <<= 1) {
        p0v += __shfl_xor(p0v, off, 64);
        p1v += __shfl_xor(p1v, off, 64);
    }
    if (lane == 0) {
        out[(size_t)row * 2 + 0] = p0v + fc_b[0];
        out[(size_t)row * 2 + 1] = p1v + fc_b[1];
    }
}

extern "C" void kernel_launch(void* const* d_in, const int* in_sizes, int n_in,
                              void* d_out, int out_size, void* d_ws, size_t ws_size,
                              hipStream_t stream) {
    const float* ts        = (const float*)d_in[0];
    const float* shapelets = (const float*)d_in[1];
    const float* fc_w      = (const float*)d_in[2];
    const float* fc_b      = (const float*)d_in[3];
    float* out = (float*)d_out;

    shapelet_r12<<<NB / 4, 256, 0, stream>>>(ts, shapelets, fc_w, fc_b, out);
}